// Round 21
// baseline (146.481 us; speedup 1.0000x reference)
//
#include <hip/hip_runtime.h>

#define DIM 64
#define NPB 256          // nodes per bucket (bucket id = dst >> 8)
#define MAXBUCK 512      // N up to 131072
#define CHUNK 4096       // edges per binning block (R17: 1024 -> atomic storm)
#define BCAP 8192        // fixed bucket capacity (mean 4092, +64 sigma safe)
#define BSTRIDE 16       // bcur padding: 1 counter per 64B line (R17 lesson)

__device__ __forceinline__ unsigned short f2bf(float v) {
    unsigned u = __float_as_uint(v);
    unsigned r = (u + 0x7fffu + ((u >> 16) & 1u)) >> 16;  // RNE
    return (unsigned short)r;
}

// h = x @ W -> bf16. Thread = 4 nodes x 4 dims; per k: 2x ds_read_b128 + 16 FMA.
// unroll capped (R14: full unroll -> VGPR spill -> 1 GB scratch traffic).
__global__ void gcn_matmul(const float* __restrict__ x, const float* __restrict__ W,
                           unsigned short* __restrict__ hbf, int N) {
    __shared__ float Wl[DIM * DIM];    // 16 KB row-major [k][d]
    __shared__ float xsT[DIM][68];     // 17 KB transposed x tile [k][node]
    int tid = threadIdx.x;
    for (int i = tid; i < 1024; i += 256)
        ((float4*)Wl)[i] = ((const float4*)W)[i];
    int node0 = blockIdx.x * 64;
#pragma unroll
    for (int rep = 0; rep < 4; ++rep) {
        int i = rep * 256 + tid;       // 0..1023
        int nn = i >> 4;               // node-in-block 0..63
        int c4 = (i & 15) * 4;         // feature base
        int gn = node0 + nn;
        float4 v;
        if (gn < N) v = *(const float4*)(x + (long)gn * DIM + c4);
        else { v.x = v.y = v.z = v.w = 0.f; }
        xsT[c4 + 0][nn] = v.x;
        xsT[c4 + 1][nn] = v.y;
        xsT[c4 + 2][nn] = v.z;
        xsT[c4 + 3][nn] = v.w;
    }
    __syncthreads();

    int lane = tid & 63, wv_ = tid >> 6;
    int d4 = (lane & 15) * 4;          // dim base
    int n0 = wv_ * 16 + (lane >> 4) * 4;  // node base (4 nodes)
    float4 a0, a1, a2, a3;
    a0.x = a0.y = a0.z = a0.w = 0.f;
    a1.x = a1.y = a1.z = a1.w = 0.f;
    a2.x = a2.y = a2.z = a2.w = 0.f;
    a3.x = a3.y = a3.z = a3.w = 0.f;
#pragma unroll 2
    for (int k = 0; k < DIM; ++k) {
        float4 wr = *(const float4*)&Wl[k * DIM + d4];
        float4 xv = *(const float4*)&xsT[k][n0];
        a0.x += xv.x * wr.x; a0.y += xv.x * wr.y; a0.z += xv.x * wr.z; a0.w += xv.x * wr.w;
        a1.x += xv.y * wr.x; a1.y += xv.y * wr.y; a1.z += xv.y * wr.z; a1.w += xv.y * wr.w;
        a2.x += xv.z * wr.x; a2.y += xv.z * wr.y; a2.z += xv.z * wr.z; a2.w += xv.z * wr.w;
        a3.x += xv.w * wr.x; a3.y += xv.w * wr.y; a3.z += xv.w * wr.z; a3.w += xv.w * wr.w;
    }
#define STORE_NODE(j, aj)                                                   \
    {                                                                       \
        int gn = node0 + n0 + j;                                            \
        if (gn < N) {                                                       \
            uint2 p;                                                       \
            p.x = (unsigned)f2bf(aj.x) | ((unsigned)f2bf(aj.y) << 16);      \
            p.y = (unsigned)f2bf(aj.z) | ((unsigned)f2bf(aj.w) << 16);      \
            *(uint2*)(hbf + (long)gn * DIM + d4) = p;                       \
        }                                                                   \
    }
    STORE_NODE(0, a0) STORE_NODE(1, a1) STORE_NODE(2, a2) STORE_NODE(3, a3)
#undef STORE_NODE
}

// bcur[i*BSTRIDE] = i * BCAP  (padded cursors; replaces count+scan)
__global__ void init_bcur(int* __restrict__ bcur, int nbuck) {
    int i = blockIdx.x * 256 + threadIdx.x;
    if (i < nbuck) bcur[i * BSTRIDE] = i * BCAP;
}

// bin edges into fixed-capacity bucket regions; entry = (src<<8) | (dst&255)
__global__ void bin_edges(const int* __restrict__ ei, int* __restrict__ bcur,
                          unsigned* __restrict__ binned, int E, int nbuck) {
    __shared__ int hist[MAXBUCK];
    int tid = threadIdx.x;
    long e0 = (long)blockIdx.x * CHUNK;
    for (int i = tid; i < nbuck; i += 256) hist[i] = 0;
    __syncthreads();
    int s[16], t[16];
#pragma unroll
    for (int it = 0; it < 16; ++it) {
        long e = e0 + it * 256 + tid;
        if (e < E) {
            s[it] = ei[e];
            t[it] = ei[E + e];
            atomicAdd(&hist[t[it] >> 8], 1);
        } else {
            s[it] = -1;
        }
    }
    __syncthreads();
    // reserve contiguous range per (block,bucket); hist becomes local cursor
    for (int i = tid; i < nbuck; i += 256) {
        int c = hist[i];
        hist[i] = c ? atomicAdd(&bcur[i * BSTRIDE], c) : 0;
    }
    __syncthreads();
#pragma unroll
    for (int it = 0; it < 16; ++it) {
        if (s[it] >= 0) {
            int b = t[it] >> 8;
            int p = atomicAdd(&hist[b], 1);
            binned[p] = ((unsigned)s[it] << 8) | (unsigned)(t[it] & 255);
        }
    }
}

// per-bucket LDS counting sort -> gapped per-node CSR (adj, off, ncnt, dinv)
__global__ void bucket_sort(const int* __restrict__ bcur, const unsigned* __restrict__ binned,
                            int* __restrict__ off, int* __restrict__ ncnt,
                            int* __restrict__ adj, float* __restrict__ dinv, int N) {
    __shared__ int lcur[NPB];
    __shared__ int sh[NPB];
    int bid = blockIdx.x, tid = threadIdx.x;  // 512 threads
    int node0 = bid << 8;
    int e0 = bid * BCAP;
    int e1 = bcur[bid * BSTRIDE];             // final cursor = region end
    if (tid < NPB) lcur[tid] = 0;
    __syncthreads();
    for (int e = e0 + tid; e < e1; e += 512)
        atomicAdd(&lcur[binned[e] & 255], 1);
    __syncthreads();
    int v = 0;
    if (tid < NPB) { v = lcur[tid]; sh[tid] = v; }
    __syncthreads();
    for (int d = 1; d < NPB; d <<= 1) {
        int t = (tid < NPB && tid >= d) ? sh[tid - d] : 0;
        __syncthreads();
        if (tid < NPB) sh[tid] += t;
        __syncthreads();
    }
    if (tid < NPB) {
        int excl = sh[tid] - v;
        lcur[tid] = excl;
        int node = node0 + tid;
        if (node < N) {
            off[node] = e0 + excl;
            ncnt[node] = v;
            dinv[node] = rsqrtf((float)v + 1.0f);
        }
    }
    __syncthreads();
    for (int e = e0 + tid; e < e1; e += 512) {
        unsigned u = binned[e];
        int p = atomicAdd(&lcur[u & 255], 1);
        adj[e0 + p] = (int)(u >> 8);
    }
}

// Half-feature gather pass: one wave per node, 32 features (one 64B line/edge).
// lane = (sub = lane>>4 edge slot 0..3, f2 = lane&15 feature pair within half).
// 32-edge batches -> 8 loads in flight; instruction count per edge matches the
// full-row version, but hot hb slice per pass is 6.4 MB (vs 12.8) -> L2 residency.
__global__ void gather_half(const int* __restrict__ off, const int* __restrict__ ncnt,
                            const int* __restrict__ adj,
                            const unsigned* __restrict__ hb, const float* __restrict__ dinv,
                            const float2* __restrict__ x2, const float2* __restrict__ b2,
                            float2* __restrict__ o2, int N, int pass) {
    int node = blockIdx.x * 4 + (threadIdx.x >> 6);
    int lane = threadIdx.x & 63;
    if (node >= N) return;
    int sub = lane >> 4;     // edge slot 0..3
    int f2 = lane & 15;      // feature-pair index within half
    const unsigned* hbh = hb + pass * 16;   // half-row base (row stride 32 uints)
    int start = off[node];
    int m = ncnt[node];
    float dn = dinv[node];
    unsigned us = hbh[(long)node * 32 + f2];   // self-loop half-row (hoisted)
    float2 acc; acc.x = 0.f; acc.y = 0.f;

    for (int c = 0; c < m; c += 64) {
        int rem = m - c;
        int take = rem < 64 ? rem : 64;
        int s = (lane < take) ? adj[start + c + lane] : 0;
        float w = (lane < take) ? dinv[s] : 0.f;
        for (int i = 0; i < take; i += 32) {
            // 8 load instructions, 4 edges each; padded slots read row 0 (hot, w=0)
#define G(j)                                                            \
            {                                                           \
                int idx = i + j * 4 + sub;                              \
                int ts = __shfl(s, idx);                                \
                float tw = __shfl(w, idx);                              \
                unsigned u = hbh[(long)ts * 32 + f2];                   \
                acc.x += __uint_as_float(u << 16) * tw;                 \
                acc.y += __uint_as_float(u & 0xffff0000u) * tw;         \
            }
            G(0) G(1) G(2) G(3) G(4) G(5) G(6) G(7)
#undef G
        }
    }
    // reduce the 4 edge-slot partials (xor over sub bits 4,5)
    acc.x += __shfl_xor(acc.x, 16); acc.y += __shfl_xor(acc.y, 16);
    acc.x += __shfl_xor(acc.x, 32); acc.y += __shfl_xor(acc.y, 32);
    // self loop (post-merge)
    acc.x += __uint_as_float(us << 16) * dn;
    acc.y += __uint_as_float(us & 0xffff0000u) * dn;

    if (sub == 0) {
        long gi = (long)node * 32 + pass * 16 + f2;
        float2 bb = b2[pass * 16 + f2];
        float2 xx = x2[gi];
        float2 r;
        r.x = xx.x + fmaxf(acc.x * dn + bb.x, 0.f);
        r.y = xx.y + fmaxf(acc.y * dn + bb.y, 0.f);
        o2[gi] = r;
    }
}

extern "C" void kernel_launch(void* const* d_in, const int* in_sizes, int n_in,
                              void* d_out, int out_size, void* d_ws, size_t ws_size,
                              hipStream_t stream) {
    const float* x = (const float*)d_in[0];
    const int* ei  = (const int*)d_in[1];
    const float* W = (const float*)d_in[2];
    const float* b = (const float*)d_in[3];
    float* out = (float*)d_out;

    int N = in_sizes[0] / DIM;
    int E = in_sizes[1] / 2;
    int nbuck = (N + NPB - 1) / NPB;  // 391

    char* ws = (char*)d_ws;
    size_t o = 0;
    unsigned short* hbf = (unsigned short*)(ws + o); o += (size_t)N * DIM * sizeof(unsigned short);
    float* dinv  = (float*)(ws + o); o += (size_t)N * sizeof(float);
    int*   off   = (int*)(ws + o);   o += (size_t)N * sizeof(int);
    int*   ncnt  = (int*)(ws + o);   o += (size_t)N * sizeof(int);
    int*   bcur  = (int*)(ws + o);   o += (size_t)nbuck * BSTRIDE * sizeof(int);
    unsigned* binned = (unsigned*)(ws + o); o += (size_t)nbuck * BCAP * sizeof(unsigned);
    int*   adj   = (int*)(ws + o);   o += (size_t)nbuck * BCAP * sizeof(int);

    gcn_matmul<<<(N + 63) / 64, 256, 0, stream>>>(x, W, hbf, N);
    init_bcur<<<(nbuck + 255) / 256, 256, 0, stream>>>(bcur, nbuck);
    bin_edges<<<(E + CHUNK - 1) / CHUNK, 256, 0, stream>>>(ei, bcur, binned, E, nbuck);
    bucket_sort<<<nbuck, 512, 0, stream>>>(bcur, binned, off, ncnt, adj, dinv, N);
    gather_half<<<(N + 3) / 4, 256, 0, stream>>>(off, ncnt, adj, (const unsigned*)hbf, dinv,
                                                 (const float2*)x, (const float2*)b,
                                                 (float2*)out, N, 0);
    gather_half<<<(N + 3) / 4, 256, 0, stream>>>(off, ncnt, adj, (const unsigned*)hbf, dinv,
                                                 (const float2*)x, (const float2*)b,
                                                 (float2*)out, N, 1);
}

// Round 22
// 102.390 us; speedup vs baseline: 1.4306x; 1.4306x over previous
//
#include <hip/hip_runtime.h>

#define DIM 64
#define NPB 256          // nodes per bucket (bucket id = dst >> 8)
#define MAXBUCK 512      // N up to 131072
#define CHUNK 4096       // edges per binning block (R17: 1024 -> atomic storm)
#define BCAP 8192        // fixed bucket capacity (mean 4092, +64 sigma safe)
#define BSTRIDE 16       // bcur padding: 1 counter per 64B line (R17 lesson)

__device__ __forceinline__ unsigned short f2bf(float v) {
    unsigned u = __float_as_uint(v);
    unsigned r = (u + 0x7fffu + ((u >> 16) & 1u)) >> 16;  // RNE
    return (unsigned short)r;
}

// Fat kernel: blocks [0, binB) run edge binning; blocks [binB, ...) run matmul.
// The two phases are data-independent (matmul: x,W->hbf; bin: ei->binned) and
// overlap here instead of serializing on the stream. LDS aliased via buf.
__global__ void __launch_bounds__(256)
fused_mm_bin(const float* __restrict__ x, const float* __restrict__ W,
             unsigned short* __restrict__ hbf, int N,
             const int* __restrict__ ei, int* __restrict__ bcur,
             unsigned* __restrict__ binned, int E, int nbuck, int binB) {
    __shared__ __align__(16) char buf[(DIM * DIM + DIM * 68) * 4];  // 33 KB
    int tid = threadIdx.x;

    if (blockIdx.x < binB) {
        // ---- edge binning (bucket regions at i*BCAP; cursors memset to 0) ----
        int* hist = (int*)buf;
        long e0 = (long)blockIdx.x * CHUNK;
        for (int i = tid; i < nbuck; i += 256) hist[i] = 0;
        __syncthreads();
        int s[16], t[16];
#pragma unroll
        for (int it = 0; it < 16; ++it) {
            long e = e0 + it * 256 + tid;
            if (e < E) {
                s[it] = ei[e];
                t[it] = ei[E + e];
                atomicAdd(&hist[t[it] >> 8], 1);
            } else {
                s[it] = -1;
            }
        }
        __syncthreads();
        // reserve contiguous range per (block,bucket); hist -> global cursor
        for (int i = tid; i < nbuck; i += 256) {
            int c = hist[i];
            hist[i] = c ? (i * BCAP + atomicAdd(&bcur[i * BSTRIDE], c)) : 0;
        }
        __syncthreads();
#pragma unroll
        for (int it = 0; it < 16; ++it) {
            if (s[it] >= 0) {
                int b = t[it] >> 8;
                int p = atomicAdd(&hist[b], 1);
                binned[p] = ((unsigned)s[it] << 8) | (unsigned)(t[it] & 255);
            }
        }
        return;
    }

    // ---- matmul: thread = 4 nodes x 4 dims; per k: 2x ds_read_b128 + 16 FMA.
    // unroll capped (R14: full unroll -> VGPR spill -> 1 GB scratch traffic).
    float* Wl = (float*)buf;                       // [64][64]
    float (*xsT)[68] = (float(*)[68])(buf + DIM * DIM * 4);  // [64][68]
    for (int i = tid; i < 1024; i += 256)
        ((float4*)Wl)[i] = ((const float4*)W)[i];
    int node0 = (blockIdx.x - binB) * 64;
#pragma unroll
    for (int rep = 0; rep < 4; ++rep) {
        int i = rep * 256 + tid;
        int nn = i >> 4, c4 = (i & 15) * 4;
        int gn = node0 + nn;
        float4 v;
        if (gn < N) v = *(const float4*)(x + (long)gn * DIM + c4);
        else { v.x = v.y = v.z = v.w = 0.f; }
        xsT[c4 + 0][nn] = v.x;
        xsT[c4 + 1][nn] = v.y;
        xsT[c4 + 2][nn] = v.z;
        xsT[c4 + 3][nn] = v.w;
    }
    __syncthreads();

    int lane = tid & 63, wv_ = tid >> 6;
    int d4 = (lane & 15) * 4;
    int n0 = wv_ * 16 + (lane >> 4) * 4;
    float4 a0, a1, a2, a3;
    a0.x = a0.y = a0.z = a0.w = 0.f;
    a1.x = a1.y = a1.z = a1.w = 0.f;
    a2.x = a2.y = a2.z = a2.w = 0.f;
    a3.x = a3.y = a3.z = a3.w = 0.f;
#pragma unroll 2
    for (int k = 0; k < DIM; ++k) {
        float4 wr = *(const float4*)&Wl[k * DIM + d4];
        float4 xv = *(const float4*)&xsT[k][n0];
        a0.x += xv.x * wr.x; a0.y += xv.x * wr.y; a0.z += xv.x * wr.z; a0.w += xv.x * wr.w;
        a1.x += xv.y * wr.x; a1.y += xv.y * wr.y; a1.z += xv.y * wr.z; a1.w += xv.y * wr.w;
        a2.x += xv.z * wr.x; a2.y += xv.z * wr.y; a2.z += xv.z * wr.z; a2.w += xv.z * wr.w;
        a3.x += xv.w * wr.x; a3.y += xv.w * wr.y; a3.z += xv.w * wr.z; a3.w += xv.w * wr.w;
    }
#define STORE_NODE(j, aj)                                                   \
    {                                                                       \
        int gn = node0 + n0 + j;                                            \
        if (gn < N) {                                                       \
            uint2 p;                                                       \
            p.x = (unsigned)f2bf(aj.x) | ((unsigned)f2bf(aj.y) << 16);      \
            p.y = (unsigned)f2bf(aj.z) | ((unsigned)f2bf(aj.w) << 16);      \
            *(uint2*)(hbf + (long)gn * DIM + d4) = p;                       \
        }                                                                   \
    }
    STORE_NODE(0, a0) STORE_NODE(1, a1) STORE_NODE(2, a2) STORE_NODE(3, a3)
#undef STORE_NODE
}

// per-bucket LDS counting sort -> gapped per-node CSR (adj, off, ncnt, dinv)
__global__ void bucket_sort(const int* __restrict__ bcur, const unsigned* __restrict__ binned,
                            int* __restrict__ off, int* __restrict__ ncnt,
                            int* __restrict__ adj, float* __restrict__ dinv, int N) {
    __shared__ int lcur[NPB];
    __shared__ int sh[NPB];
    int bid = blockIdx.x, tid = threadIdx.x;  // 512 threads
    int node0 = bid << 8;
    int e0 = bid * BCAP;
    int e1 = e0 + bcur[bid * BSTRIDE];        // zero-based cursor = bucket count
    if (tid < NPB) lcur[tid] = 0;
    __syncthreads();
    for (int e = e0 + tid; e < e1; e += 512)
        atomicAdd(&lcur[binned[e] & 255], 1);
    __syncthreads();
    int v = 0;
    if (tid < NPB) { v = lcur[tid]; sh[tid] = v; }
    __syncthreads();
    for (int d = 1; d < NPB; d <<= 1) {
        int t = (tid < NPB && tid >= d) ? sh[tid - d] : 0;
        __syncthreads();
        if (tid < NPB) sh[tid] += t;
        __syncthreads();
    }
    if (tid < NPB) {
        int excl = sh[tid] - v;
        lcur[tid] = excl;
        int node = node0 + tid;
        if (node < N) {
            off[node] = e0 + excl;
            ncnt[node] = v;
            dinv[node] = rsqrtf((float)v + 1.0f);
        }
    }
    __syncthreads();
    for (int e = e0 + tid; e < e1; e += 512) {
        unsigned u = binned[e];
        int p = atomicAdd(&lcur[u & 255], 1);
        adj[e0 + p] = (int)(u >> 8);
    }
}

// TWO nodes per wave: 16 hb loads in flight (2 independent 8-load streams).
// At the random-fetch floor (~104 MB, R20/R21 confirmed) — do not touch.
__global__ void gather_agg(const int* __restrict__ off, const int* __restrict__ ncnt,
                           const int* __restrict__ adj,
                           const unsigned* __restrict__ hb, const float* __restrict__ dinv,
                           const float2* __restrict__ x2, const float2* __restrict__ b2,
                           float2* __restrict__ o2, int N) {
    int wid = threadIdx.x >> 6;
    int lane = threadIdx.x & 63;
    int nodeA = blockIdx.x * 8 + wid * 2;
    int nodeB = nodeA + 1;
    if (nodeA >= N) return;
    bool hasB = (nodeB < N);
    int sub = lane >> 5;
    int f = lane & 31;
    int startA = off[nodeA];
    int mA = ncnt[nodeA];
    int startB = hasB ? off[nodeB] : 0;
    int mB = hasB ? ncnt[nodeB] : 0;
    float dnA = dinv[nodeA];
    float dnB = hasB ? dinv[nodeB] : 0.f;
    unsigned usA = hb[(long)nodeA * 32 + f];
    unsigned usB = hasB ? hb[(long)nodeB * 32 + f] : 0u;
    float2 accA; accA.x = 0.f; accA.y = 0.f;
    float2 accB; accB.x = 0.f; accB.y = 0.f;

    int mmax = mA > mB ? mA : mB;
    for (int c = 0; c < mmax; c += 64) {
        int takeA = mA - c; if (takeA > 64) takeA = 64;
        int takeB = mB - c; if (takeB > 64) takeB = 64;
        int sA = (lane < takeA) ? adj[startA + c + lane] : 0;
        float wA = (lane < takeA) ? dinv[sA] : 0.f;
        int sB = (lane < takeB) ? adj[startB + c + lane] : 0;
        float wB = (lane < takeB) ? dinv[sB] : 0.f;
        int tmax = takeA > takeB ? takeA : takeB;
        for (int i = 0; i < tmax; i += 16) {
            unsigned uA0 = 0, uA1 = 0, uA2 = 0, uA3 = 0, uA4 = 0, uA5 = 0, uA6 = 0, uA7 = 0;
            unsigned uB0 = 0, uB1 = 0, uB2 = 0, uB3 = 0, uB4 = 0, uB5 = 0, uB6 = 0, uB7 = 0;
            float qA0 = 0, qA1 = 0, qA2 = 0, qA3 = 0, qA4 = 0, qA5 = 0, qA6 = 0, qA7 = 0;
            float qB0 = 0, qB1 = 0, qB2 = 0, qB3 = 0, qB4 = 0, qB5 = 0, qB6 = 0, qB7 = 0;
            if (i < takeA) {
                int i0 = i + 0 + sub, i1 = i + 2 + sub, i2 = i + 4 + sub, i3 = i + 6 + sub;
                int i4 = i + 8 + sub, i5 = i + 10 + sub, i6 = i + 12 + sub, i7 = i + 14 + sub;
                int t0 = __shfl(sA, i0), t1 = __shfl(sA, i1), t2 = __shfl(sA, i2), t3 = __shfl(sA, i3);
                int t4 = __shfl(sA, i4), t5 = __shfl(sA, i5), t6 = __shfl(sA, i6), t7 = __shfl(sA, i7);
                qA0 = __shfl(wA, i0); qA1 = __shfl(wA, i1); qA2 = __shfl(wA, i2); qA3 = __shfl(wA, i3);
                qA4 = __shfl(wA, i4); qA5 = __shfl(wA, i5); qA6 = __shfl(wA, i6); qA7 = __shfl(wA, i7);
                uA0 = hb[(long)t0 * 32 + f]; uA1 = hb[(long)t1 * 32 + f];
                uA2 = hb[(long)t2 * 32 + f]; uA3 = hb[(long)t3 * 32 + f];
                uA4 = hb[(long)t4 * 32 + f]; uA5 = hb[(long)t5 * 32 + f];
                uA6 = hb[(long)t6 * 32 + f]; uA7 = hb[(long)t7 * 32 + f];
            }
            if (i < takeB) {
                int i0 = i + 0 + sub, i1 = i + 2 + sub, i2 = i + 4 + sub, i3 = i + 6 + sub;
                int i4 = i + 8 + sub, i5 = i + 10 + sub, i6 = i + 12 + sub, i7 = i + 14 + sub;
                int t0 = __shfl(sB, i0), t1 = __shfl(sB, i1), t2 = __shfl(sB, i2), t3 = __shfl(sB, i3);
                int t4 = __shfl(sB, i4), t5 = __shfl(sB, i5), t6 = __shfl(sB, i6), t7 = __shfl(sB, i7);
                qB0 = __shfl(wB, i0); qB1 = __shfl(wB, i1); qB2 = __shfl(wB, i2); qB3 = __shfl(wB, i3);
                qB4 = __shfl(wB, i4); qB5 = __shfl(wB, i5); qB6 = __shfl(wB, i6); qB7 = __shfl(wB, i7);
                uB0 = hb[(long)t0 * 32 + f]; uB1 = hb[(long)t1 * 32 + f];
                uB2 = hb[(long)t2 * 32 + f]; uB3 = hb[(long)t3 * 32 + f];
                uB4 = hb[(long)t4 * 32 + f]; uB5 = hb[(long)t5 * 32 + f];
                uB6 = hb[(long)t6 * 32 + f]; uB7 = hb[(long)t7 * 32 + f];
            }
#define ACC(acc, u, q)                                                  \
            acc.x += __uint_as_float(u << 16) * q;                      \
            acc.y += __uint_as_float(u & 0xffff0000u) * q;
            ACC(accA, uA0, qA0) ACC(accA, uA1, qA1) ACC(accA, uA2, qA2) ACC(accA, uA3, qA3)
            ACC(accA, uA4, qA4) ACC(accA, uA5, qA5) ACC(accA, uA6, qA6) ACC(accA, uA7, qA7)
            ACC(accB, uB0, qB0) ACC(accB, uB1, qB1) ACC(accB, uB2, qB2) ACC(accB, uB3, qB3)
            ACC(accB, uB4, qB4) ACC(accB, uB5, qB5) ACC(accB, uB6, qB6) ACC(accB, uB7, qB7)
#undef ACC
        }
    }
    accA.x += __shfl_xor(accA.x, 32);
    accA.y += __shfl_xor(accA.y, 32);
    accB.x += __shfl_xor(accB.x, 32);
    accB.y += __shfl_xor(accB.y, 32);
    accA.x += __uint_as_float(usA << 16) * dnA;
    accA.y += __uint_as_float(usA & 0xffff0000u) * dnA;
    accB.x += __uint_as_float(usB << 16) * dnB;
    accB.y += __uint_as_float(usB & 0xffff0000u) * dnB;

    int wn = (lane < 32) ? nodeA : nodeB;
    float2 wacc = (lane < 32) ? accA : accB;
    float dnw = (lane < 32) ? dnA : dnB;
    if (wn < N) {
        long gi = (long)wn * 32 + f;
        float2 bb = b2[f];
        float2 xx = x2[gi];
        float2 r;
        r.x = xx.x + fmaxf(wacc.x * dnw + bb.x, 0.f);
        r.y = xx.y + fmaxf(wacc.y * dnw + bb.y, 0.f);
        o2[gi] = r;
    }
}

extern "C" void kernel_launch(void* const* d_in, const int* in_sizes, int n_in,
                              void* d_out, int out_size, void* d_ws, size_t ws_size,
                              hipStream_t stream) {
    const float* x = (const float*)d_in[0];
    const int* ei  = (const int*)d_in[1];
    const float* W = (const float*)d_in[2];
    const float* b = (const float*)d_in[3];
    float* out = (float*)d_out;

    int N = in_sizes[0] / DIM;
    int E = in_sizes[1] / 2;
    int nbuck = (N + NPB - 1) / NPB;  // 391

    char* ws = (char*)d_ws;
    size_t o = 0;
    unsigned short* hbf = (unsigned short*)(ws + o); o += (size_t)N * DIM * sizeof(unsigned short);
    float* dinv  = (float*)(ws + o); o += (size_t)N * sizeof(float);
    int*   off   = (int*)(ws + o);   o += (size_t)N * sizeof(int);
    int*   ncnt  = (int*)(ws + o);   o += (size_t)N * sizeof(int);
    int*   bcur  = (int*)(ws + o);   o += (size_t)nbuck * BSTRIDE * sizeof(int);
    unsigned* binned = (unsigned*)(ws + o); o += (size_t)nbuck * BCAP * sizeof(unsigned);
    int*   adj   = (int*)(ws + o);   o += (size_t)nbuck * BCAP * sizeof(int);

    int binB = (E + CHUNK - 1) / CHUNK;          // 391 binning blocks (first)
    int mmB  = (N + 63) / 64;                    // 1563 matmul blocks

    hipMemsetAsync(bcur, 0, (size_t)nbuck * BSTRIDE * sizeof(int), stream);
    fused_mm_bin<<<binB + mmB, 256, 0, stream>>>(x, W, hbf, N, ei, bcur,
                                                 binned, E, nbuck, binB);
    bucket_sort<<<nbuck, 512, 0, stream>>>(bcur, binned, off, ncnt, adj, dinv, N);
    gather_agg<<<(N + 7) / 8, 256, 0, stream>>>(off, ncnt, adj, (const unsigned*)hbf, dinv,
                                                (const float2*)x, (const float2*)b,
                                                (float2*)out, N);
}